// Round 1
// 149.024 us; speedup vs baseline: 1.0309x; 1.0309x over previous
//
#include <hip/hip_runtime.h>
#include <math.h>

#define BH   32
#define NSEQ 2048
#define DH   64
#define NH   16
#define LOG2E 1.44269504088896f

typedef _Float16 f16x8 __attribute__((ext_vector_type(8)));
typedef __fp16   fp16x2 __attribute__((ext_vector_type(2)));
typedef float    f32x16v __attribute__((ext_vector_type(16)));
typedef unsigned uint2v __attribute__((ext_vector_type(2)));

#if __has_builtin(__builtin_amdgcn_exp2f)
#define EXP2F(x) __builtin_amdgcn_exp2f(x)
#else
#define EXP2F(x) exp2f(x)
#endif

static __device__ __forceinline__ unsigned pkrtz(float a, float b) {
    fp16x2 r = __builtin_amdgcn_cvt_pkrtz(a, b);
    return __builtin_bit_cast(unsigned, r);
}
static __device__ __forceinline__ unsigned packh_rne(float a, float b) {
    union { _Float16 h[2]; unsigned u; } x;
    x.h[0] = (_Float16)a; x.h[1] = (_Float16)b;
    return x.u;
}
#if __has_builtin(__builtin_amdgcn_perm)
#define PERM(a, b, s) __builtin_amdgcn_perm((a), (b), (s))
#else
static __device__ __forceinline__ unsigned PERM(unsigned a, unsigned b, unsigned s) {
    if (s == 0x05040100u) return (b & 0xffffu) | (a << 16);
    return (b >> 16) | (a & 0xffff0000u);
}
#endif

// cos/sin of pos * 10000^(-p/32) via revolutions + hw transcendentals
static __device__ __forceinline__ float2 rope_cs(int pos, int p) {
    float invf_rev = EXP2F(-(float)p * (13.287712379549449f / 32.0f)) * 0.15915494309189535f;
    float rev = (float)pos * invf_rev;
    float fr = rev - floorf(rev);
    float th = fr * 6.283185307179586f;
    return make_float2(__cosf(th), __sinf(th));
}

// ---------------- fused prep: q-norm/rope, k-norm/rope, v-pack ---------------
// grid.x: [0,8192) q blocks (8 rows), [8192,16384) k blocks, [16384,17408) v tiles.
__global__ __launch_bounds__(256) void prep_all(
    const float* __restrict__ q, const float* __restrict__ k, const float* __restrict__ v,
    const float* __restrict__ qs, const float* __restrict__ ksc,
    unsigned* __restrict__ qh, unsigned* __restrict__ kh, unsigned* __restrict__ vt2) {
    const int bid = blockIdx.x;
    const int t = threadIdx.x;
    if (bid < 16384) {
        const bool isq = bid < 8192;
        const float* in = isq ? q : k;
        const float* sc = isq ? qs : ksc;
        unsigned* outp  = isq ? qh : kh;
        const float smul = isq ? 0.125f * LOG2E : 1.0f;
        const int sb = bid & 8191;
        const int w = t >> 6, lane = t & 63;
        const int c = lane & 31, hfr = lane >> 5;
        const int row = sb * 8 + w * 2 + hfr;
        float2 x2 = *(const float2*)(in + (size_t)row * DH + 2 * c);
        float ss = x2.x * x2.x + x2.y * x2.y;
        #pragma unroll
        for (int off = 16; off > 0; off >>= 1) ss += __shfl_xor(ss, off);
        float inv = 1.0f / fmaxf(sqrtf(ss), 1e-12f);
        float2 s2 = *(const float2*)(sc + 2 * c);
        float t0 = x2.x * inv * s2.x;
        float t1 = x2.y * inv * s2.y;
        float p0 = __shfl_xor(t0, 16);
        float p1 = __shfl_xor(t1, 16);
        float r0 = (c < 16) ? -p0 : p0;
        float r1 = (c < 16) ? -p1 : p1;
        int pos = row & (NSEQ - 1);
        int pp = (2 * c) & 31;
        float2 cs0 = rope_cs(pos, pp);
        float2 cs1 = rope_cs(pos, pp + 1);
        float o0 = (t0 * cs0.x + r0 * cs0.y) * smul;
        float o1 = (t1 * cs1.x + r1 * cs1.y) * smul;
        outp[row * 32 + c] = packh_rne(o0, o1);
    } else {
        // V: fp32 [bh][key][dim] -> u32 dim-pairs [bh][dp=32][key] via LDS bounce
        const int sb = bid - 16384;
        const int kt = sb & 31, bh = sb >> 5;
        __shared__ float Lv[64 * 68];
        #pragma unroll
        for (int i = 0; i < 4; ++i) {
            int chunk = t + 256 * i;
            int r = chunk >> 4, fg = chunk & 15;
            *(float4*)&Lv[r * 68 + fg * 4] =
                *(const float4*)(v + ((size_t)bh * NSEQ + kt * 64 + r) * DH + fg * 4);
        }
        __syncthreads();
        const int dp = t >> 3, kg = t & 7;
        unsigned u[8];
        #pragma unroll
        for (int j = 0; j < 8; ++j) {
            int key = kg * 8 + j;
            float2 f2 = *(const float2*)&Lv[key * 68 + 2 * dp];
            u[j] = pkrtz(f2.x, f2.y);
        }
        unsigned* dst = vt2 + ((size_t)bh * 32 + dp) * NSEQ + kt * 64 + kg * 8;
        *(uint4*)(dst + 0) = make_uint4(u[0], u[1], u[2], u[3]);
        *(uint4*)(dst + 4) = make_uint4(u[4], u[5], u[6], u[7]);
    }
}

// ---------------- flash attention: 4-wave WG, key-split wave pairs -----------
// WG 256 = 4 waves; wave w: q-rows qb*64 + (w&1)*32 + c, keys half (w>>1) of
// each 64-key tile. 1024 WGs -> 4 WGs/CU -> 16 waves/CU (4/SIMD, 2x previous).
// Same total MFMA/exp work; staging amortized over 4 waves; double-buffered
// LDS (36 KB) + register prefetch. Key-half partial O/l merged via LDS at end.
// permlane32_swap builds PV B-frags (replaces ds_bpermute + cndmask).
__global__ __launch_bounds__(256, 4) void attn_kernel(
    const unsigned* __restrict__ qh, const unsigned* __restrict__ khg,
    const unsigned* __restrict__ vt2, float* __restrict__ out) {

    __shared__ _Float16 Ks[2][64 * 72];
    __shared__ _Float16 Vs[2][64 * 72];

    const int bh = blockIdx.y, qb = blockIdx.x;
    const int tid = threadIdx.x;
    const int w = tid >> 6, lane = tid & 63;
    const int c = lane & 31, hf = lane >> 5;
    const int qhw = w & 1;   // q-row half of the WG's 64 rows
    const int khw = w >> 1;  // 32-key half of each 64-key tile

    const _Float16* qbase = (const _Float16*)qh + ((size_t)bh * NSEQ + qb * 64) * DH;
    const _Float16* kbase = (const _Float16*)khg + (size_t)bh * NSEQ * DH;
    const unsigned* vbase = vt2 + (size_t)bh * 32 * NSEQ;

    // stage K/V tile 0 (512 uint4 chunks each, 2 per thread)
    #pragma unroll
    for (int i = 0; i < 2; ++i) {
        int chunk = tid + 256 * i;
        int r = chunk >> 3, sg = chunk & 7;
        *(uint4*)&Ks[0][r * 72 + sg * 8] = *(const uint4*)(kbase + r * DH + sg * 8);
    }
    #pragma unroll
    for (int i = 0; i < 2; ++i) {
        int chunk = tid + 256 * i;
        int dp = chunk >> 4, kq = (chunk & 15) * 4;
        uint4 vr = *(const uint4*)(vbase + (size_t)dp * NSEQ + kq);
        uint2 lo, hi;
        lo.x = PERM(vr.y, vr.x, 0x05040100u); hi.x = PERM(vr.y, vr.x, 0x07060302u);
        lo.y = PERM(vr.w, vr.z, 0x05040100u); hi.y = PERM(vr.w, vr.z, 0x07060302u);
        *(uint2*)&Vs[0][(2 * dp) * 72 + kq]     = lo;
        *(uint2*)&Vs[0][(2 * dp + 1) * 72 + kq] = hi;
    }

    // Q frags from global: B[k=dim][n=qrow]
    f16x8 qf[4];
    #pragma unroll
    for (int ks = 0; ks < 4; ++ks)
        qf[ks] = *(const f16x8*)(qbase + (qhw * 32 + c) * DH + ks * 16 + hf * 8);

    f32x16v o[2];
    #pragma unroll
    for (int mt = 0; mt < 2; ++mt)
        #pragma unroll
        for (int r = 0; r < 16; ++r) o[mt][r] = 0.f;
    float lpart = 0.f;

    __syncthreads();

    for (int jt = 0; jt < 32; ++jt) {
        const int cur = jt & 1;
        uint4 kpre[2], vpre[2];
        if (jt + 1 < 32) {
            #pragma unroll
            for (int i = 0; i < 2; ++i) {
                int chunk = tid + 256 * i;
                int r = chunk >> 3, sg = chunk & 7;
                kpre[i] = *(const uint4*)(kbase + (size_t)(jt + 1) * 64 * DH + r * DH + sg * 8);
            }
            #pragma unroll
            for (int i = 0; i < 2; ++i) {
                int chunk = tid + 256 * i;
                int dp = chunk >> 4, kq = (chunk & 15) * 4;
                vpre[i] = *(const uint4*)(vbase + (size_t)dp * NSEQ + (jt + 1) * 64 + kq);
            }
        }

        // S^T (this wave's 32-key half) = K_half * Q^T
        // qrow = c, key-in-half = (r&3)+8*(r>>2)+4*hf
        f32x16v s;
        #pragma unroll
        for (int r = 0; r < 16; ++r) s[r] = 0.f;
        #pragma unroll
        for (int ks = 0; ks < 4; ++ks) {
            f16x8 ka = *(const f16x8*)&Ks[cur][(khw * 32 + c) * 72 + ks * 16 + hf * 8];
            s = __builtin_amdgcn_mfma_f32_32x32x16_f16(ka, qf[ks], s, 0, 0, 0);
        }

        // exp2 (fixed max; scores bounded by l2norm) + running denominator
        #pragma unroll
        for (int r = 0; r < 16; ++r) {
            float pv = EXP2F(s[r]);
            s[r] = pv;
            lpart += pv;
        }

        // O^T += V^T * P^T ; B-frags built in-register from C-layout
        #pragma unroll
        for (int kk = 0; kk < 2; ++kk) {
            unsigned P01 = pkrtz(s[kk * 8 + 0], s[kk * 8 + 1]);
            unsigned P23 = pkrtz(s[kk * 8 + 2], s[kk * 8 + 3]);
            unsigned P45 = pkrtz(s[kk * 8 + 4], s[kk * 8 + 5]);
            unsigned P67 = pkrtz(s[kk * 8 + 6], s[kk * 8 + 7]);
            union { unsigned u[4]; f16x8 v; } B;
#if __has_builtin(__builtin_amdgcn_permlane32_swap)
            // swap(a,b) -> { {a.lo,b.lo}, {a.hi,b.hi} } across the lane<32/>=32 split
            uint2v r02 = __builtin_amdgcn_permlane32_swap(P01, P45, 0, 0);
            uint2v r13 = __builtin_amdgcn_permlane32_swap(P23, P67, 0, 0);
            B.u[0] = r02[0]; B.u[1] = r13[0]; B.u[2] = r02[1]; B.u[3] = r13[1];
#else
            unsigned x01 = (unsigned)__shfl_xor((int)P01, 32);
            unsigned x23 = (unsigned)__shfl_xor((int)P23, 32);
            unsigned x45 = (unsigned)__shfl_xor((int)P45, 32);
            unsigned x67 = (unsigned)__shfl_xor((int)P67, 32);
            B.u[0] = hf ? x45 : P01;
            B.u[1] = hf ? x67 : P23;
            B.u[2] = hf ? P45 : x01;
            B.u[3] = hf ? P67 : x23;
#endif
            const int kc = khw * 2 + kk;
            f16x8 va0 = *(const f16x8*)&Vs[cur][c * 72 + kc * 16 + hf * 8];
            f16x8 va1 = *(const f16x8*)&Vs[cur][(32 + c) * 72 + kc * 16 + hf * 8];
            o[0] = __builtin_amdgcn_mfma_f32_32x32x16_f16(va0, B.v, o[0], 0, 0, 0);
            o[1] = __builtin_amdgcn_mfma_f32_32x32x16_f16(va1, B.v, o[1], 0, 0, 0);
        }

        // commit prefetch to other buffer
        if (jt + 1 < 32) {
            #pragma unroll
            for (int i = 0; i < 2; ++i) {
                int chunk = tid + 256 * i;
                int r = chunk >> 3, sg = chunk & 7;
                *(uint4*)&Ks[1 - cur][r * 72 + sg * 8] = kpre[i];
            }
            #pragma unroll
            for (int i = 0; i < 2; ++i) {
                int chunk = tid + 256 * i;
                int dp = chunk >> 4, kq = (chunk & 15) * 4;
                uint2 lo, hi;
                lo.x = PERM(vpre[i].y, vpre[i].x, 0x05040100u); hi.x = PERM(vpre[i].y, vpre[i].x, 0x07060302u);
                lo.y = PERM(vpre[i].w, vpre[i].z, 0x05040100u); hi.y = PERM(vpre[i].w, vpre[i].z, 0x07060302u);
                *(uint2*)&Vs[1 - cur][(2 * dp) * 72 + kq]     = lo;
                *(uint2*)&Vs[1 - cur][(2 * dp + 1) * 72 + kq] = hi;
            }
        }
        __syncthreads();
    }

    // merge key-half partials across wave pairs (w <-> w+2), normalize, store.
    // Lred reuses Ks (18.4 KB >= 128 lanes * 33 words * 4 B = 16.9 KB);
    // stride 33 -> bank = (lane + e) % 32, conflict-free.
    float lw = lpart + __shfl_xor(lpart, 32);
    float* Lred = (float*)&Ks[0][0];
    if (w >= 2) {
        const int base = ((w - 2) * 64 + lane) * 33;
        #pragma unroll
        for (int mt = 0; mt < 2; ++mt)
            #pragma unroll
            for (int r = 0; r < 16; ++r) Lred[base + mt * 16 + r] = o[mt][r];
        Lred[base + 32] = lw;
    }
    __syncthreads();
    if (w < 2) {
        const int base = (w * 64 + lane) * 33;
        #pragma unroll
        for (int mt = 0; mt < 2; ++mt)
            #pragma unroll
            for (int r = 0; r < 16; ++r) o[mt][r] += Lred[base + mt * 16 + r];
        lw += Lred[base + 32];
        float invl = 1.0f / lw;
        const int b = bh >> 4, h = bh & 15;
        const int pos = qb * 64 + w * 32 + c;
        float* obase = out + ((size_t)b * NSEQ + pos) * (NH * DH) + h * DH;
        #pragma unroll
        for (int mt = 0; mt < 2; ++mt)
            #pragma unroll
            for (int g = 0; g < 4; ++g) {
                float4 r4 = make_float4(o[mt][g * 4 + 0] * invl, o[mt][g * 4 + 1] * invl,
                                        o[mt][g * 4 + 2] * invl, o[mt][g * 4 + 3] * invl);
                *(float4*)(obase + mt * 32 + g * 8 + hf * 4) = r4;
            }
    }
}

extern "C" void kernel_launch(void* const* d_in, const int* in_sizes, int n_in,
                              void* d_out, int out_size, void* d_ws, size_t ws_size,
                              hipStream_t stream) {
    const float* q  = (const float*)d_in[0];
    const float* k  = (const float*)d_in[1];
    const float* v  = (const float*)d_in[2];
    const float* qs = (const float*)d_in[3];
    const float* ks = (const float*)d_in[4];
    float* outp = (float*)d_out;

    unsigned* qh  = (unsigned*)d_ws;                 // 8 MB
    unsigned* kh  = qh + (size_t)BH * NSEQ * 32;     // 8 MB
    unsigned* vt2 = kh + (size_t)BH * NSEQ * 32;     // 8 MB

    prep_all<<<17408, 256, 0, stream>>>(q, k, v, qs, ks, qh, kh, vt2);
    attn_kernel<<<dim3(NSEQ / 64, BH), 256, 0, stream>>>(qh, kh, vt2, outp);
}

// Round 2
// 144.585 us; speedup vs baseline: 1.0626x; 1.0307x over previous
//
#include <hip/hip_runtime.h>
#include <math.h>

#define BH   32
#define NSEQ 2048
#define DH   64
#define NH   16
#define LOG2E 1.44269504088896f

typedef _Float16 f16x8 __attribute__((ext_vector_type(8)));
typedef __fp16   fp16x2 __attribute__((ext_vector_type(2)));
typedef float    f32x16v __attribute__((ext_vector_type(16)));
typedef unsigned uint2v __attribute__((ext_vector_type(2)));

#if __has_builtin(__builtin_amdgcn_exp2f)
#define EXP2F(x) __builtin_amdgcn_exp2f(x)
#else
#define EXP2F(x) exp2f(x)
#endif

static __device__ __forceinline__ unsigned pkrtz(float a, float b) {
    fp16x2 r = __builtin_amdgcn_cvt_pkrtz(a, b);
    return __builtin_bit_cast(unsigned, r);
}
static __device__ __forceinline__ unsigned packh_rne(float a, float b) {
    union { _Float16 h[2]; unsigned u; } x;
    x.h[0] = (_Float16)a; x.h[1] = (_Float16)b;
    return x.u;
}

// cos/sin of pos * 10000^(-p/32) via revolutions + hw transcendentals
static __device__ __forceinline__ float2 rope_cs(int pos, int p) {
    float invf_rev = EXP2F(-(float)p * (13.287712379549449f / 32.0f)) * 0.15915494309189535f;
    float rev = (float)pos * invf_rev;
    float fr = rev - floorf(rev);
    float th = fr * 6.283185307179586f;
    return make_float2(__cosf(th), __sinf(th));
}

// ---------------- fused prep: q-norm/rope, k-norm/rope (frag-order), v-pack --
// grid.x: [0,8192) q blocks (8 rows), [8192,16384) k blocks, [16384,17408) v tiles.
// Q kept in [bh][row][dim] halfs (loaded once per WG in attn).
// K written in MFMA-A-frag order:  KF[bh][jt][khw][ks][hf][c][8]
//   holds K[bh][jt*64+khw*32+c][ks*16+hf*8+e]  (u32 = dim pair)
// V written in MFMA-A-frag order:  VF[bh][jt][kc][rh][hf][c][8]
//   holds V[bh][jt*64+kc*16+hf*8+e][rh*32+c]   (u32 = key pair)
// -> each attn fragment is one coalesced dwordx4 at base + lane*16.
__global__ __launch_bounds__(256) void prep_all(
    const float* __restrict__ q, const float* __restrict__ k, const float* __restrict__ v,
    const float* __restrict__ qs, const float* __restrict__ ksc,
    unsigned* __restrict__ qh, unsigned* __restrict__ kh, unsigned* __restrict__ vt2) {
    const int bid = blockIdx.x;
    const int t = threadIdx.x;
    if (bid < 16384) {
        const bool isq = bid < 8192;
        const float* in = isq ? q : k;
        const float* sc = isq ? qs : ksc;
        const float smul = isq ? 0.125f * LOG2E : 1.0f;
        const int sb = bid & 8191;
        const int w = t >> 6, lane = t & 63;
        const int c = lane & 31, hfr = lane >> 5;
        const int row = sb * 8 + w * 2 + hfr;
        float2 x2 = *(const float2*)(in + (size_t)row * DH + 2 * c);
        float ss = x2.x * x2.x + x2.y * x2.y;
        #pragma unroll
        for (int off = 16; off > 0; off >>= 1) ss += __shfl_xor(ss, off);
        float inv = 1.0f / fmaxf(sqrtf(ss), 1e-12f);
        float2 s2 = *(const float2*)(sc + 2 * c);
        float t0 = x2.x * inv * s2.x;
        float t1 = x2.y * inv * s2.y;
        float p0 = __shfl_xor(t0, 16);
        float p1 = __shfl_xor(t1, 16);
        float r0 = (c < 16) ? -p0 : p0;
        float r1 = (c < 16) ? -p1 : p1;
        int pos = row & (NSEQ - 1);
        int pp = (2 * c) & 31;
        float2 cs0 = rope_cs(pos, pp);
        float2 cs1 = rope_cs(pos, pp + 1);
        float o0 = (t0 * cs0.x + r0 * cs0.y) * smul;
        float o1 = (t1 * cs1.x + r1 * cs1.y) * smul;
        unsigned val = packh_rne(o0, o1);
        if (isq) {
            qh[row * 32 + c] = val;
        } else {
            const int rloc = row & (NSEQ - 1);
            // dims d0=2c,2c+1: ks=c>>3, hf=(c>>2)&1, pair=(c&3)
            const unsigned idx = (unsigned)((rloc >> 5) * 1024 + (c >> 3) * 256
                               + ((c >> 2) & 1) * 128 + (rloc & 31) * 4 + (c & 3));
            kh[(size_t)(row >> 11) * 65536 + idx] = val;
        }
    } else {
        // V: fp32 [bh][key][dim] -> frag-order VF via LDS bounce
        const int sb = bid - 16384;
        const int kt = sb & 31, bh = sb >> 5;
        __shared__ float Lv[64 * 68];
        #pragma unroll
        for (int i = 0; i < 4; ++i) {
            int chunk = t + 256 * i;
            int r = chunk >> 4, fg = chunk & 15;
            *(float4*)&Lv[r * 68 + fg * 4] =
                *(const float4*)(v + ((size_t)bh * NSEQ + kt * 64 + r) * DH + fg * 4);
        }
        __syncthreads();
        const int d = t & 63, kg = t >> 6;  // dim, 16-key group
        unsigned u[8];
        #pragma unroll
        for (int j = 0; j < 8; ++j) {
            int ky = kg * 16 + 2 * j;
            u[j] = pkrtz(Lv[ky * 68 + d], Lv[(ky + 1) * 68 + d]);
        }
        const int rh = d >> 5, cc = d & 31;
        unsigned* dst = vt2 + (size_t)bh * 65536
                      + (size_t)((kt * 4 + kg) * 2 + rh) * 256 + cc * 4;
        *(uint4*)(dst)       = make_uint4(u[0], u[1], u[2], u[3]);   // hf=0 (j=0..3)
        *(uint4*)(dst + 128) = make_uint4(u[4], u[5], u[6], u[7]);   // hf=1 (j=4..7)
    }
}

// ---------------- flash attention: barrier-free register streaming -----------
// 4-wave WG; wave w: q-rows qb*64+(w&1)*32+c, key-half (w>>1) of each 64-key
// tile. K/V fragments loaded straight from frag-order HBM layouts (1 coalesced
// dwordx4 per frag, L2-resident via XCD-chunked swizzle), double-buffered in
// registers with STATIC indexing (2-step unrolled loop). No LDS / no barriers
// in the main loop; 16.9 KB LDS only for the final key-half merge.
static __device__ __forceinline__ f16x8 ld8(const unsigned* p) {
    return *(const f16x8*)p;
}

static __device__ __forceinline__ void attn_step(
    const f16x8 (&kc)[4], const f16x8 (&vc)[4],
    f16x8 (&kn)[4], f16x8 (&vn)[4],
    const unsigned* kp, const unsigned* vp, bool pre,
    const f16x8 (&qf)[4], f32x16v (&o)[2], float& lpart, int hf)
{
    if (pre) {  // issue next-tile loads first; latency hides under MFMA+exp
        #pragma unroll
        for (int ks = 0; ks < 4; ++ks) kn[ks] = ld8(kp + ks * 256);
        #pragma unroll
        for (int kk = 0; kk < 2; ++kk)
            #pragma unroll
            for (int rh = 0; rh < 2; ++rh)
                vn[kk * 2 + rh] = ld8(vp + kk * 512 + rh * 256);
    }
    // S^T (this wave's 32-key half) = K_half * Q^T
    f32x16v s;
    #pragma unroll
    for (int r = 0; r < 16; ++r) s[r] = 0.f;
    #pragma unroll
    for (int ks = 0; ks < 4; ++ks)
        s = __builtin_amdgcn_mfma_f32_32x32x16_f16(kc[ks], qf[ks], s, 0, 0, 0);
    // exp2 (fixed max; scores bounded by l2norm) + running denominator
    #pragma unroll
    for (int r = 0; r < 16; ++r) {
        float pv = EXP2F(s[r]);
        s[r] = pv;
        lpart += pv;
    }
    // O^T += V^T * P^T ; B-frags built in-register from C-layout
    #pragma unroll
    for (int kk = 0; kk < 2; ++kk) {
        unsigned P01 = pkrtz(s[kk * 8 + 0], s[kk * 8 + 1]);
        unsigned P23 = pkrtz(s[kk * 8 + 2], s[kk * 8 + 3]);
        unsigned P45 = pkrtz(s[kk * 8 + 4], s[kk * 8 + 5]);
        unsigned P67 = pkrtz(s[kk * 8 + 6], s[kk * 8 + 7]);
        union { unsigned u[4]; f16x8 v; } B;
#if __has_builtin(__builtin_amdgcn_permlane32_swap)
        uint2v r02 = __builtin_amdgcn_permlane32_swap(P01, P45, 0, 0);
        uint2v r13 = __builtin_amdgcn_permlane32_swap(P23, P67, 0, 0);
        B.u[0] = r02[0]; B.u[1] = r13[0]; B.u[2] = r02[1]; B.u[3] = r13[1];
#else
        unsigned x01 = (unsigned)__shfl_xor((int)P01, 32);
        unsigned x23 = (unsigned)__shfl_xor((int)P23, 32);
        unsigned x45 = (unsigned)__shfl_xor((int)P45, 32);
        unsigned x67 = (unsigned)__shfl_xor((int)P67, 32);
        B.u[0] = hf ? x45 : P01;
        B.u[1] = hf ? x67 : P23;
        B.u[2] = hf ? P45 : x01;
        B.u[3] = hf ? P67 : x23;
#endif
        o[0] = __builtin_amdgcn_mfma_f32_32x32x16_f16(vc[kk * 2 + 0], B.v, o[0], 0, 0, 0);
        o[1] = __builtin_amdgcn_mfma_f32_32x32x16_f16(vc[kk * 2 + 1], B.v, o[1], 0, 0, 0);
    }
}

__global__ __launch_bounds__(256, 3) void attn_kernel(
    const unsigned* __restrict__ qh, const unsigned* __restrict__ kf,
    const unsigned* __restrict__ vf, float* __restrict__ out) {

    __shared__ float Lred[128 * 33];  // 16.9 KB epilogue merge only

    // bijective XCD-chunked swizzle: XCD x owns contiguous flat [x*128,(x+1)*128)
    // -> each XCD's resident WGs share ~4 bh of K/V (~2 MB, L2-resident)
    const int flat = (blockIdx.x & 7) * 128 + (blockIdx.x >> 3);
    const int bh = flat >> 5, qb = flat & 31;

    const int tid = threadIdx.x;
    const int w = tid >> 6, lane = tid & 63;
    const int c = lane & 31, hf = lane >> 5;
    const int qhw = w & 1;   // q-row half
    const int khw = w >> 1;  // 32-key half of each 64-key tile

    // Q frags (one-time): B[k=dim][n=qrow]
    const _Float16* qbase = (const _Float16*)qh + ((size_t)bh * NSEQ + qb * 64) * DH;
    f16x8 qf[4];
    #pragma unroll
    for (int ks = 0; ks < 4; ++ks)
        qf[ks] = *(const f16x8*)(qbase + (qhw * 32 + c) * DH + ks * 16 + hf * 8);

    // frag-order bases: + jt*2048 per tile; ks*256 / kk*512+rh*256 fold to imms
    const unsigned* kfb = kf + (size_t)bh * 65536 + khw * 1024 + lane * 4;
    const unsigned* vfb = vf + (size_t)bh * 65536 + khw * 1024 + lane * 4;

    f16x8 ka[4], va[4], kb[4], vb[4];
    #pragma unroll
    for (int ks = 0; ks < 4; ++ks) ka[ks] = ld8(kfb + ks * 256);
    #pragma unroll
    for (int kk = 0; kk < 2; ++kk)
        #pragma unroll
        for (int rh = 0; rh < 2; ++rh)
            va[kk * 2 + rh] = ld8(vfb + kk * 512 + rh * 256);

    f32x16v o[2];
    #pragma unroll
    for (int mt = 0; mt < 2; ++mt)
        #pragma unroll
        for (int r = 0; r < 16; ++r) o[mt][r] = 0.f;
    float lpart = 0.f;

    for (int jt = 0; jt < 32; jt += 2) {
        attn_step(ka, va, kb, vb,
                  kfb + (size_t)(jt + 1) * 2048, vfb + (size_t)(jt + 1) * 2048,
                  true, qf, o, lpart, hf);
        attn_step(kb, vb, ka, va,
                  kfb + (size_t)(jt + 2) * 2048, vfb + (size_t)(jt + 2) * 2048,
                  jt + 2 < 32, qf, o, lpart, hf);
    }

    // merge key-half partials across wave pairs (w <-> w+2), normalize, store.
    // stride 33 -> conflict-free.
    float lw = lpart + __shfl_xor(lpart, 32);
    if (w >= 2) {
        const int base = ((w - 2) * 64 + lane) * 33;
        #pragma unroll
        for (int mt = 0; mt < 2; ++mt)
            #pragma unroll
            for (int r = 0; r < 16; ++r) Lred[base + mt * 16 + r] = o[mt][r];
        Lred[base + 32] = lw;
    }
    __syncthreads();
    if (w < 2) {
        const int base = (w * 64 + lane) * 33;
        #pragma unroll
        for (int mt = 0; mt < 2; ++mt)
            #pragma unroll
            for (int r = 0; r < 16; ++r) o[mt][r] += Lred[base + mt * 16 + r];
        lw += Lred[base + 32];
        float invl = 1.0f / lw;
        const int b = bh >> 4, h = bh & 15;
        const int pos = qb * 64 + w * 32 + c;
        float* obase = out + ((size_t)b * NSEQ + pos) * (NH * DH) + h * DH;
        #pragma unroll
        for (int mt = 0; mt < 2; ++mt)
            #pragma unroll
            for (int g = 0; g < 4; ++g) {
                float4 r4 = make_float4(o[mt][g * 4 + 0] * invl, o[mt][g * 4 + 1] * invl,
                                        o[mt][g * 4 + 2] * invl, o[mt][g * 4 + 3] * invl);
                *(float4*)(obase + mt * 32 + g * 8 + hf * 4) = r4;
            }
    }
}

extern "C" void kernel_launch(void* const* d_in, const int* in_sizes, int n_in,
                              void* d_out, int out_size, void* d_ws, size_t ws_size,
                              hipStream_t stream) {
    const float* q  = (const float*)d_in[0];
    const float* k  = (const float*)d_in[1];
    const float* v  = (const float*)d_in[2];
    const float* qs = (const float*)d_in[3];
    const float* ks = (const float*)d_in[4];
    float* outp = (float*)d_out;

    unsigned* qh  = (unsigned*)d_ws;                 // 8 MB
    unsigned* kh  = qh + (size_t)BH * NSEQ * 32;     // 8 MB
    unsigned* vt2 = kh + (size_t)BH * NSEQ * 32;     // 8 MB

    prep_all<<<17408, 256, 0, stream>>>(q, k, v, qs, ks, qh, kh, vt2);
    attn_kernel<<<1024, 256, 0, stream>>>(qh, kh, vt2, outp);
}

// Round 3
// 143.579 us; speedup vs baseline: 1.0700x; 1.0070x over previous
//
#include <hip/hip_runtime.h>
#include <math.h>

#define BH   32
#define NSEQ 2048
#define DH   64
#define NH   16
#define LOG2E 1.44269504088896f

typedef _Float16 f16x8 __attribute__((ext_vector_type(8)));
typedef __fp16   fp16x2 __attribute__((ext_vector_type(2)));
typedef _Float16 half2v __attribute__((ext_vector_type(2)));
typedef float    f32x16v __attribute__((ext_vector_type(16)));
typedef unsigned uint2v __attribute__((ext_vector_type(2)));

#if __has_builtin(__builtin_amdgcn_exp2f)
#define EXP2F(x) __builtin_amdgcn_exp2f(x)
#else
#define EXP2F(x) exp2f(x)
#endif

static __device__ __forceinline__ unsigned pkrtz(float a, float b) {
    fp16x2 r = __builtin_amdgcn_cvt_pkrtz(a, b);
    return __builtin_bit_cast(unsigned, r);
}
static __device__ __forceinline__ unsigned packh_rne(float a, float b) {
    union { _Float16 h[2]; unsigned u; } x;
    x.h[0] = (_Float16)a; x.h[1] = (_Float16)b;
    return x.u;
}

// cos/sin of pos * 10000^(-p/32) via revolutions + hw transcendentals
static __device__ __forceinline__ float2 rope_cs(int pos, int p) {
    float invf_rev = EXP2F(-(float)p * (13.287712379549449f / 32.0f)) * 0.15915494309189535f;
    float rev = (float)pos * invf_rev;
    float fr = rev - floorf(rev);
    float th = fr * 6.283185307179586f;
    return make_float2(__cosf(th), __sinf(th));
}

// ---------------- fused prep: q-norm/rope, k-norm/rope (frag-order), v-pack --
// grid.x: [0,8192) q blocks (8 rows), [8192,16384) k blocks, [16384,17408) v tiles.
// Q kept in [bh][row][dim] halfs (loaded once per WG in attn).
// K written in MFMA-A-frag order:  KF[bh][jt][khw][ks][hf][c][8]
// V written in MFMA-A-frag order:  VF[bh][jt][kc][rh][hf][c][8]
// -> each attn fragment is one coalesced dwordx4 at base + lane*16.
__global__ __launch_bounds__(256) void prep_all(
    const float* __restrict__ q, const float* __restrict__ k, const float* __restrict__ v,
    const float* __restrict__ qs, const float* __restrict__ ksc,
    unsigned* __restrict__ qh, unsigned* __restrict__ kh, unsigned* __restrict__ vt2) {
    const int bid = blockIdx.x;
    const int t = threadIdx.x;
    if (bid < 16384) {
        const bool isq = bid < 8192;
        const float* in = isq ? q : k;
        const float* sc = isq ? qs : ksc;
        const float smul = isq ? 0.125f * LOG2E : 1.0f;
        const int sb = bid & 8191;
        const int w = t >> 6, lane = t & 63;
        const int c = lane & 31, hfr = lane >> 5;
        const int row = sb * 8 + w * 2 + hfr;
        float2 x2 = *(const float2*)(in + (size_t)row * DH + 2 * c);
        float ss = x2.x * x2.x + x2.y * x2.y;
        #pragma unroll
        for (int off = 16; off > 0; off >>= 1) ss += __shfl_xor(ss, off);
        float inv = 1.0f / fmaxf(sqrtf(ss), 1e-12f);
        float2 s2 = *(const float2*)(sc + 2 * c);
        float t0 = x2.x * inv * s2.x;
        float t1 = x2.y * inv * s2.y;
        float p0 = __shfl_xor(t0, 16);
        float p1 = __shfl_xor(t1, 16);
        float r0 = (c < 16) ? -p0 : p0;
        float r1 = (c < 16) ? -p1 : p1;
        int pos = row & (NSEQ - 1);
        int pp = (2 * c) & 31;
        float2 cs0 = rope_cs(pos, pp);
        float2 cs1 = rope_cs(pos, pp + 1);
        float o0 = (t0 * cs0.x + r0 * cs0.y) * smul;
        float o1 = (t1 * cs1.x + r1 * cs1.y) * smul;
        unsigned val = packh_rne(o0, o1);
        if (isq) {
            qh[row * 32 + c] = val;
        } else {
            const int rloc = row & (NSEQ - 1);
            const unsigned idx = (unsigned)((rloc >> 5) * 1024 + (c >> 3) * 256
                               + ((c >> 2) & 1) * 128 + (rloc & 31) * 4 + (c & 3));
            kh[(size_t)(row >> 11) * 65536 + idx] = val;
        }
    } else {
        // V: fp32 [bh][key][dim] -> frag-order VF via LDS bounce
        const int sb = bid - 16384;
        const int kt = sb & 31, bh = sb >> 5;
        __shared__ float Lv[64 * 68];
        #pragma unroll
        for (int i = 0; i < 4; ++i) {
            int chunk = t + 256 * i;
            int r = chunk >> 4, fg = chunk & 15;
            *(float4*)&Lv[r * 68 + fg * 4] =
                *(const float4*)(v + ((size_t)bh * NSEQ + kt * 64 + r) * DH + fg * 4);
        }
        __syncthreads();
        const int d = t & 63, kg = t >> 6;  // dim, 16-key group
        unsigned u[8];
        #pragma unroll
        for (int j = 0; j < 8; ++j) {
            int ky = kg * 16 + 2 * j;
            u[j] = pkrtz(Lv[ky * 68 + d], Lv[(ky + 1) * 68 + d]);
        }
        const int rh = d >> 5, cc = d & 31;
        unsigned* dst = vt2 + (size_t)bh * 65536
                      + (size_t)((kt * 4 + kg) * 2 + rh) * 256 + cc * 4;
        *(uint4*)(dst)       = make_uint4(u[0], u[1], u[2], u[3]);   // hf=0
        *(uint4*)(dst + 128) = make_uint4(u[4], u[5], u[6], u[7]);   // hf=1
    }
}

// ---------------- flash attention: reg streaming, 2 q-tiles per wave ---------
// 4-wave WG covers 128 q-rows; wave w: key-half (w>>1), q-subtiles (w&1) and
// (w&1)+2 (rows +0/+64). Each K/V fragment load feeds TWO independent MFMA
// chains -> VMEM traffic halved vs 1-tile, ILP doubled. Grid 512 = 2 WGs/CU.
// No LDS/barriers in main loop; lpart via v_dot2 on packed P (consistent with
// PV numerator); hoisted zero C-operand kills per-step acc re-init movs.
static __device__ __forceinline__ f16x8 ld8(const unsigned* p) {
    return *(const f16x8*)p;
}

static __device__ __forceinline__ void pv_tile(
    f32x16v& s, const f16x8 (&vc)[4], f32x16v (&ot)[2], float& lp, int hf)
{
    #pragma unroll
    for (int r = 0; r < 16; ++r) s[r] = EXP2F(s[r]);
    #pragma unroll
    for (int kk = 0; kk < 2; ++kk) {
        unsigned P01 = pkrtz(s[kk * 8 + 0], s[kk * 8 + 1]);
        unsigned P23 = pkrtz(s[kk * 8 + 2], s[kk * 8 + 3]);
        unsigned P45 = pkrtz(s[kk * 8 + 4], s[kk * 8 + 5]);
        unsigned P67 = pkrtz(s[kk * 8 + 6], s[kk * 8 + 7]);
#if __has_builtin(__builtin_amdgcn_fdot2)
        const half2v one2 = {(_Float16)1.0f, (_Float16)1.0f};
        lp = __builtin_amdgcn_fdot2(__builtin_bit_cast(half2v, P01), one2, lp, false);
        lp = __builtin_amdgcn_fdot2(__builtin_bit_cast(half2v, P23), one2, lp, false);
        lp = __builtin_amdgcn_fdot2(__builtin_bit_cast(half2v, P45), one2, lp, false);
        lp = __builtin_amdgcn_fdot2(__builtin_bit_cast(half2v, P67), one2, lp, false);
#else
        #pragma unroll
        for (int r = 0; r < 8; ++r) lp += s[kk * 8 + r];
#endif
        union { unsigned u[4]; f16x8 v; } B;
#if __has_builtin(__builtin_amdgcn_permlane32_swap)
        uint2v r02 = __builtin_amdgcn_permlane32_swap(P01, P45, 0, 0);
        uint2v r13 = __builtin_amdgcn_permlane32_swap(P23, P67, 0, 0);
        B.u[0] = r02[0]; B.u[1] = r13[0]; B.u[2] = r02[1]; B.u[3] = r13[1];
#else
        unsigned x01 = (unsigned)__shfl_xor((int)P01, 32);
        unsigned x23 = (unsigned)__shfl_xor((int)P23, 32);
        unsigned x45 = (unsigned)__shfl_xor((int)P45, 32);
        unsigned x67 = (unsigned)__shfl_xor((int)P67, 32);
        B.u[0] = hf ? x45 : P01;
        B.u[1] = hf ? x67 : P23;
        B.u[2] = hf ? P45 : x01;
        B.u[3] = hf ? P67 : x23;
#endif
        ot[0] = __builtin_amdgcn_mfma_f32_32x32x16_f16(vc[kk * 2 + 0], B.v, ot[0], 0, 0, 0);
        ot[1] = __builtin_amdgcn_mfma_f32_32x32x16_f16(vc[kk * 2 + 1], B.v, ot[1], 0, 0, 0);
    }
}

static __device__ __forceinline__ void attn_step(
    const f16x8 (&kc)[4], const f16x8 (&vc)[4],
    f16x8 (&kn)[4], f16x8 (&vn)[4],
    const unsigned* kp, const unsigned* vp, bool pre,
    const f16x8 (&qf)[2][4], f32x16v (&o)[2][2], float (&lp)[2],
    const f32x16v& z16, int hf)
{
    if (pre) {  // issue next-tile loads first; latency hides under MFMA+exp
        #pragma unroll
        for (int ks = 0; ks < 4; ++ks) kn[ks] = ld8(kp + ks * 256);
        #pragma unroll
        for (int kk = 0; kk < 2; ++kk)
            #pragma unroll
            for (int rh = 0; rh < 2; ++rh)
                vn[kk * 2 + rh] = ld8(vp + kk * 512 + rh * 256);
    }
    // two independent S^T chains off the same K fragments
    f32x16v s0 = __builtin_amdgcn_mfma_f32_32x32x16_f16(kc[0], qf[0][0], z16, 0, 0, 0);
    f32x16v s1 = __builtin_amdgcn_mfma_f32_32x32x16_f16(kc[0], qf[1][0], z16, 0, 0, 0);
    #pragma unroll
    for (int ks = 1; ks < 4; ++ks) {
        s0 = __builtin_amdgcn_mfma_f32_32x32x16_f16(kc[ks], qf[0][ks], s0, 0, 0, 0);
        s1 = __builtin_amdgcn_mfma_f32_32x32x16_f16(kc[ks], qf[1][ks], s1, 0, 0, 0);
    }
    pv_tile(s0, vc, o[0], lp[0], hf);
    pv_tile(s1, vc, o[1], lp[1], hf);
}

__global__ __launch_bounds__(256, 2) void attn_kernel(
    const unsigned* __restrict__ qh, const unsigned* __restrict__ kf,
    const unsigned* __restrict__ vf, float* __restrict__ out) {

    __shared__ float Lred[128 * 33];  // 16.9 KB, epilogue merge only

    // bijective XCD-chunked swizzle: XCD x owns flat [x*64,(x+1)*64) = 4 bh
    // -> ~2 MB K/V per XCD, L2-resident
    const int flat = (blockIdx.x & 7) * 64 + (blockIdx.x >> 3);
    const int bh = flat >> 4, qb = flat & 15;   // 16 q-blocks of 128 rows

    const int tid = threadIdx.x;
    const int w = tid >> 6, lane = tid & 63;
    const int c = lane & 31, hf = lane >> 5;
    const int qhw = w & 1;   // 32-row slot within each 64-row half
    const int khw = w >> 1;  // 32-key half of each 64-key tile

    // Q frags (one-time): B[k=dim][n=qrow], two q-subtiles (rows +0 / +64)
    const _Float16* qbase = (const _Float16*)qh + ((size_t)bh * NSEQ + qb * 128) * DH;
    f16x8 qf[2][4];
    #pragma unroll
    for (int t = 0; t < 2; ++t)
        #pragma unroll
        for (int ks = 0; ks < 4; ++ks)
            qf[t][ks] = *(const f16x8*)(qbase + (t * 64 + qhw * 32 + c) * DH + ks * 16 + hf * 8);

    const unsigned* kfb = kf + (size_t)bh * 65536 + khw * 1024 + lane * 4;
    const unsigned* vfb = vf + (size_t)bh * 65536 + khw * 1024 + lane * 4;

    f16x8 ka[4], va[4], kb[4], vb[4];
    #pragma unroll
    for (int ks = 0; ks < 4; ++ks) ka[ks] = ld8(kfb + ks * 256);
    #pragma unroll
    for (int kk = 0; kk < 2; ++kk)
        #pragma unroll
        for (int rh = 0; rh < 2; ++rh)
            va[kk * 2 + rh] = ld8(vfb + kk * 512 + rh * 256);

    f32x16v z16;
    #pragma unroll
    for (int r = 0; r < 16; ++r) z16[r] = 0.f;

    f32x16v o[2][2];
    #pragma unroll
    for (int t = 0; t < 2; ++t)
        #pragma unroll
        for (int mt = 0; mt < 2; ++mt)
            #pragma unroll
            for (int r = 0; r < 16; ++r) o[t][mt][r] = 0.f;
    float lp[2] = {0.f, 0.f};

    for (int jt = 0; jt < 32; jt += 2) {
        attn_step(ka, va, kb, vb,
                  kfb + (size_t)(jt + 1) * 2048, vfb + (size_t)(jt + 1) * 2048,
                  true, qf, o, lp, z16, hf);
        attn_step(kb, vb, ka, va,
                  kfb + (size_t)(jt + 2) * 2048, vfb + (size_t)(jt + 2) * 2048,
                  jt + 2 < 32, qf, o, lp, z16, hf);
    }

    // merge key-half partials across wave pairs (w <-> w+2); two phases reuse
    // the same Lred buffer. stride 33 -> conflict-free.
    float lw[2];
    #pragma unroll
    for (int t = 0; t < 2; ++t) lw[t] = lp[t] + __shfl_xor(lp[t], 32);

    const int b = bh >> 4, h = bh & 15;
    #pragma unroll
    for (int t = 0; t < 2; ++t) {
        if (t) __syncthreads();  // WAR: phase-0 reads done before phase-1 writes
        if (w >= 2) {
            const int base = ((w - 2) * 64 + lane) * 33;
            #pragma unroll
            for (int mt = 0; mt < 2; ++mt)
                #pragma unroll
                for (int r = 0; r < 16; ++r) Lred[base + mt * 16 + r] = o[t][mt][r];
            Lred[base + 32] = lw[t];
        }
        __syncthreads();
        if (w < 2) {
            const int base = (w * 64 + lane) * 33;
            #pragma unroll
            for (int mt = 0; mt < 2; ++mt)
                #pragma unroll
                for (int r = 0; r < 16; ++r) o[t][mt][r] += Lred[base + mt * 16 + r];
            float invl = 1.0f / (lw[t] + Lred[base + 32]);
            const int pos = qb * 128 + t * 64 + w * 32 + c;
            float* obase = out + ((size_t)b * NSEQ + pos) * (NH * DH) + h * DH;
            #pragma unroll
            for (int mt = 0; mt < 2; ++mt)
                #pragma unroll
                for (int g = 0; g < 4; ++g) {
                    float4 r4 = make_float4(o[t][mt][g * 4 + 0] * invl, o[t][mt][g * 4 + 1] * invl,
                                            o[t][mt][g * 4 + 2] * invl, o[t][mt][g * 4 + 3] * invl);
                    *(float4*)(obase + mt * 32 + g * 8 + hf * 4) = r4;
                }
        }
    }
}

extern "C" void kernel_launch(void* const* d_in, const int* in_sizes, int n_in,
                              void* d_out, int out_size, void* d_ws, size_t ws_size,
                              hipStream_t stream) {
    const float* q  = (const float*)d_in[0];
    const float* k  = (const float*)d_in[1];
    const float* v  = (const float*)d_in[2];
    const float* qs = (const float*)d_in[3];
    const float* ks = (const float*)d_in[4];
    float* outp = (float*)d_out;

    unsigned* qh  = (unsigned*)d_ws;                 // 8 MB
    unsigned* kh  = qh + (size_t)BH * NSEQ * 32;     // 8 MB
    unsigned* vt2 = kh + (size_t)BH * NSEQ * 32;     // 8 MB

    prep_all<<<17408, 256, 0, stream>>>(q, k, v, qs, ks, qh, kh, vt2);
    attn_kernel<<<512, 256, 0, stream>>>(qh, kh, vt2, outp);
}

// Round 4
// 140.843 us; speedup vs baseline: 1.0908x; 1.0194x over previous
//
#include <hip/hip_runtime.h>
#include <math.h>

#define BH   32
#define NSEQ 2048
#define DH   64
#define NH   16
#define LOG2E 1.44269504088896f

typedef _Float16 f16x8 __attribute__((ext_vector_type(8)));
typedef __fp16   fp16x2 __attribute__((ext_vector_type(2)));
typedef _Float16 half2v __attribute__((ext_vector_type(2)));
typedef float    f32x16v __attribute__((ext_vector_type(16)));
typedef unsigned uint2v __attribute__((ext_vector_type(2)));

#if __has_builtin(__builtin_amdgcn_exp2f)
#define EXP2F(x) __builtin_amdgcn_exp2f(x)
#else
#define EXP2F(x) exp2f(x)
#endif

static __device__ __forceinline__ unsigned pkrtz(float a, float b) {
    fp16x2 r = __builtin_amdgcn_cvt_pkrtz(a, b);
    return __builtin_bit_cast(unsigned, r);
}
static __device__ __forceinline__ unsigned packh_rne(float a, float b) {
    union { _Float16 h[2]; unsigned u; } x;
    x.h[0] = (_Float16)a; x.h[1] = (_Float16)b;
    return x.u;
}

// cos/sin of pos * 10000^(-p/32) via revolutions + hw transcendentals
static __device__ __forceinline__ float2 rope_cs(int pos, int p) {
    float invf_rev = EXP2F(-(float)p * (13.287712379549449f / 32.0f)) * 0.15915494309189535f;
    float rev = (float)pos * invf_rev;
    float fr = rev - floorf(rev);
    float th = fr * 6.283185307179586f;
    return make_float2(__cosf(th), __sinf(th));
}

// ---------------- fused prep: q-norm/rope, k-norm/rope (frag-order), v-pack --
// grid.x: [0,8192) q blocks (8 rows), [8192,16384) k blocks, [16384,17408) v tiles.
// Q kept in [bh][row][dim] halfs (loaded once per WG in attn).
// K written in MFMA-A-frag order:  KF[bh][jt][khw][ks][hf][c][8]
// V written in MFMA-A-frag order:  VF[bh][jt][kc][rh][hf][c][8]
// -> each attn fragment is one coalesced dwordx4 at base + lane*16.
__global__ __launch_bounds__(256) void prep_all(
    const float* __restrict__ q, const float* __restrict__ k, const float* __restrict__ v,
    const float* __restrict__ qs, const float* __restrict__ ksc,
    unsigned* __restrict__ qh, unsigned* __restrict__ kh, unsigned* __restrict__ vt2) {
    const int bid = blockIdx.x;
    const int t = threadIdx.x;
    if (bid < 16384) {
        const bool isq = bid < 8192;
        const float* in = isq ? q : k;
        const float* sc = isq ? qs : ksc;
        const float smul = isq ? 0.125f * LOG2E : 1.0f;
        const int sb = bid & 8191;
        const int w = t >> 6, lane = t & 63;
        const int c = lane & 31, hfr = lane >> 5;
        const int row = sb * 8 + w * 2 + hfr;
        float2 x2 = *(const float2*)(in + (size_t)row * DH + 2 * c);
        float ss = x2.x * x2.x + x2.y * x2.y;
        #pragma unroll
        for (int off = 16; off > 0; off >>= 1) ss += __shfl_xor(ss, off);
        float inv = 1.0f / fmaxf(sqrtf(ss), 1e-12f);
        float2 s2 = *(const float2*)(sc + 2 * c);
        float t0 = x2.x * inv * s2.x;
        float t1 = x2.y * inv * s2.y;
        float p0 = __shfl_xor(t0, 16);
        float p1 = __shfl_xor(t1, 16);
        float r0 = (c < 16) ? -p0 : p0;
        float r1 = (c < 16) ? -p1 : p1;
        int pos = row & (NSEQ - 1);
        int pp = (2 * c) & 31;
        float2 cs0 = rope_cs(pos, pp);
        float2 cs1 = rope_cs(pos, pp + 1);
        float o0 = (t0 * cs0.x + r0 * cs0.y) * smul;
        float o1 = (t1 * cs1.x + r1 * cs1.y) * smul;
        unsigned val = packh_rne(o0, o1);
        if (isq) {
            qh[row * 32 + c] = val;
        } else {
            const int rloc = row & (NSEQ - 1);
            const unsigned idx = (unsigned)((rloc >> 5) * 1024 + (c >> 3) * 256
                               + ((c >> 2) & 1) * 128 + (rloc & 31) * 4 + (c & 3));
            kh[(size_t)(row >> 11) * 65536 + idx] = val;
        }
    } else {
        // V: fp32 [bh][key][dim] -> frag-order VF via LDS bounce
        const int sb = bid - 16384;
        const int kt = sb & 31, bh = sb >> 5;
        __shared__ float Lv[64 * 68];
        #pragma unroll
        for (int i = 0; i < 4; ++i) {
            int chunk = t + 256 * i;
            int r = chunk >> 4, fg = chunk & 15;
            *(float4*)&Lv[r * 68 + fg * 4] =
                *(const float4*)(v + ((size_t)bh * NSEQ + kt * 64 + r) * DH + fg * 4);
        }
        __syncthreads();
        const int d = t & 63, kg = t >> 6;  // dim, 16-key group
        unsigned u[8];
        #pragma unroll
        for (int j = 0; j < 8; ++j) {
            int ky = kg * 16 + 2 * j;
            u[j] = pkrtz(Lv[ky * 68 + d], Lv[(ky + 1) * 68 + d]);
        }
        const int rh = d >> 5, cc = d & 31;
        unsigned* dst = vt2 + (size_t)bh * 65536
                      + (size_t)((kt * 4 + kg) * 2 + rh) * 256 + cc * 4;
        *(uint4*)(dst)       = make_uint4(u[0], u[1], u[2], u[3]);   // hf=0
        *(uint4*)(dst + 128) = make_uint4(u[4], u[5], u[6], u[7]);   // hf=1
    }
}

// ---------------- flash attention: software-pipelined register streaming -----
// 4-wave WG covers 128 q-rows; wave w: key-half (w>>1), q-subtiles (w&1)
// rows +0/+64. 2-tile pipeline: QK(tile j+1) issues BEFORE softmax+PV(tile j)
// so the QK MFMA chain latency hides under the previous tile's VALU work.
// K/V single-buffered in regs (reload after consumer; ~1 step of slack >> L2
// latency); s double-buffered. No LDS/barriers in main loop; setprio around
// MFMA clusters. Grid 512 = 2 WGs/CU.
static __device__ __forceinline__ f16x8 ld8(const unsigned* p) {
    return *(const f16x8*)p;
}

static __device__ __forceinline__ void load_k(f16x8 (&kd)[4], const unsigned* p) {
    #pragma unroll
    for (int ks = 0; ks < 4; ++ks) kd[ks] = ld8(p + ks * 256);
}
static __device__ __forceinline__ void load_v(f16x8 (&vd)[4], const unsigned* p) {
    #pragma unroll
    for (int kk = 0; kk < 2; ++kk)
        #pragma unroll
        for (int rh = 0; rh < 2; ++rh)
            vd[kk * 2 + rh] = ld8(p + kk * 512 + rh * 256);
}

// QK for both q-subtiles: s0/s1 = K_half * Q^T (results used NEXT step)
static __device__ __forceinline__ void qk2(
    const f16x8 (&kc)[4], const f16x8 (&qf)[2][4], const f32x16v& z16,
    f32x16v& s0, f32x16v& s1)
{
    __builtin_amdgcn_s_setprio(1);
    s0 = __builtin_amdgcn_mfma_f32_32x32x16_f16(kc[0], qf[0][0], z16, 0, 0, 0);
    s1 = __builtin_amdgcn_mfma_f32_32x32x16_f16(kc[0], qf[1][0], z16, 0, 0, 0);
    #pragma unroll
    for (int ks = 1; ks < 4; ++ks) {
        s0 = __builtin_amdgcn_mfma_f32_32x32x16_f16(kc[ks], qf[0][ks], s0, 0, 0, 0);
        s1 = __builtin_amdgcn_mfma_f32_32x32x16_f16(kc[ks], qf[1][ks], s1, 0, 0, 0);
    }
    __builtin_amdgcn_s_setprio(0);
}

// softmax (fixed max) + PV for one q-subtile
static __device__ __forceinline__ void pv_tile(
    f32x16v& s, const f16x8 (&vc)[4], f32x16v (&ot)[2], float& lp, int hf)
{
    #pragma unroll
    for (int r = 0; r < 16; ++r) s[r] = EXP2F(s[r]);
    #pragma unroll
    for (int kk = 0; kk < 2; ++kk) {
        unsigned P01 = pkrtz(s[kk * 8 + 0], s[kk * 8 + 1]);
        unsigned P23 = pkrtz(s[kk * 8 + 2], s[kk * 8 + 3]);
        unsigned P45 = pkrtz(s[kk * 8 + 4], s[kk * 8 + 5]);
        unsigned P67 = pkrtz(s[kk * 8 + 6], s[kk * 8 + 7]);
#if __has_builtin(__builtin_amdgcn_fdot2)
        const half2v one2 = {(_Float16)1.0f, (_Float16)1.0f};
        lp = __builtin_amdgcn_fdot2(__builtin_bit_cast(half2v, P01), one2, lp, false);
        lp = __builtin_amdgcn_fdot2(__builtin_bit_cast(half2v, P23), one2, lp, false);
        lp = __builtin_amdgcn_fdot2(__builtin_bit_cast(half2v, P45), one2, lp, false);
        lp = __builtin_amdgcn_fdot2(__builtin_bit_cast(half2v, P67), one2, lp, false);
#else
        #pragma unroll
        for (int r = 0; r < 8; ++r) lp += s[kk * 8 + r];
#endif
        union { unsigned u[4]; f16x8 v; } B;
#if __has_builtin(__builtin_amdgcn_permlane32_swap)
        uint2v r02 = __builtin_amdgcn_permlane32_swap(P01, P45, 0, 0);
        uint2v r13 = __builtin_amdgcn_permlane32_swap(P23, P67, 0, 0);
        B.u[0] = r02[0]; B.u[1] = r13[0]; B.u[2] = r02[1]; B.u[3] = r13[1];
#else
        unsigned x01 = (unsigned)__shfl_xor((int)P01, 32);
        unsigned x23 = (unsigned)__shfl_xor((int)P23, 32);
        unsigned x45 = (unsigned)__shfl_xor((int)P45, 32);
        unsigned x67 = (unsigned)__shfl_xor((int)P67, 32);
        B.u[0] = hf ? x45 : P01;
        B.u[1] = hf ? x67 : P23;
        B.u[2] = hf ? P45 : x01;
        B.u[3] = hf ? P67 : x23;
#endif
        __builtin_amdgcn_s_setprio(1);
        ot[0] = __builtin_amdgcn_mfma_f32_32x32x16_f16(vc[kk * 2 + 0], B.v, ot[0], 0, 0, 0);
        ot[1] = __builtin_amdgcn_mfma_f32_32x32x16_f16(vc[kk * 2 + 1], B.v, ot[1], 0, 0, 0);
        __builtin_amdgcn_s_setprio(0);
    }
}

static __device__ __forceinline__ void smpv2(
    f32x16v& s0, f32x16v& s1, const f16x8 (&vc)[4],
    f32x16v (&o)[2][2], float (&lp)[2], int hf)
{
    pv_tile(s0, vc, o[0], lp[0], hf);
    pv_tile(s1, vc, o[1], lp[1], hf);
}

__global__ __launch_bounds__(256, 2) void attn_kernel(
    const unsigned* __restrict__ qh, const unsigned* __restrict__ kf,
    const unsigned* __restrict__ vf, float* __restrict__ out) {

    __shared__ float Lred[128 * 33];  // 16.9 KB, epilogue merge only

    // bijective XCD-chunked swizzle: XCD x owns flat [x*64,(x+1)*64) = 4 bh
    const int flat = (blockIdx.x & 7) * 64 + (blockIdx.x >> 3);
    const int bh = flat >> 4, qb = flat & 15;   // 16 q-blocks of 128 rows

    const int tid = threadIdx.x;
    const int w = tid >> 6, lane = tid & 63;
    const int c = lane & 31, hf = lane >> 5;
    const int qhw = w & 1;   // 32-row slot within each 64-row half
    const int khw = w >> 1;  // 32-key half of each 64-key tile

    // Q frags (one-time): B[k=dim][n=qrow], two q-subtiles (rows +0 / +64)
    const _Float16* qbase = (const _Float16*)qh + ((size_t)bh * NSEQ + qb * 128) * DH;
    f16x8 qf[2][4];
    #pragma unroll
    for (int t = 0; t < 2; ++t)
        #pragma unroll
        for (int ks = 0; ks < 4; ++ks)
            qf[t][ks] = *(const f16x8*)(qbase + (t * 64 + qhw * 32 + c) * DH + ks * 16 + hf * 8);

    const unsigned* kfb = kf + (size_t)bh * 65536 + khw * 1024 + lane * 4;
    const unsigned* vfb = vf + (size_t)bh * 65536 + khw * 1024 + lane * 4;

    f32x16v z16;
    #pragma unroll
    for (int r = 0; r < 16; ++r) z16[r] = 0.f;

    f32x16v o[2][2];
    #pragma unroll
    for (int t = 0; t < 2; ++t)
        #pragma unroll
        for (int mt = 0; mt < 2; ++mt)
            #pragma unroll
            for (int r = 0; r < 16; ++r) o[t][mt][r] = 0.f;
    float lp[2] = {0.f, 0.f};

    f16x8 kc[4], vc[4];
    f32x16v sA0, sA1, sB0, sB1;

    // prologue: K(0),V(0) -> s(0) ; issue K(1)
    load_k(kc, kfb);
    load_v(vc, vfb);
    qk2(kc, qf, z16, sA0, sA1);          // s(0)
    load_k(kc, kfb + 2048);              // K(1)

    for (int jt = 0; jt < 32; jt += 2) {
        // even step: consume sA=s(jt), V(jt); produce sB=s(jt+1)
        qk2(kc, qf, z16, sB0, sB1);                       // QK(jt+1), uses K(jt+1)
        if (jt + 2 < 32) load_k(kc, kfb + (size_t)(jt + 2) * 2048);
        smpv2(sA0, sA1, vc, o, lp, hf);                   // SM(jt) + PV(V(jt))
        load_v(vc, vfb + (size_t)(jt + 1) * 2048);        // V(jt+1)

        // odd step: consume sB=s(jt+1), V(jt+1); produce sA=s(jt+2)
        if (jt + 2 < 32) {
            qk2(kc, qf, z16, sA0, sA1);                   // QK(jt+2), uses K(jt+2)
            if (jt + 3 < 32) load_k(kc, kfb + (size_t)(jt + 3) * 2048);
        }
        smpv2(sB0, sB1, vc, o, lp, hf);                   // SM(jt+1) + PV(V(jt+1))
        if (jt + 2 < 32) load_v(vc, vfb + (size_t)(jt + 2) * 2048);
    }

    // merge key-half partials across wave pairs (w <-> w+2); two phases reuse
    // the same Lred buffer. stride 33 -> conflict-free.
    float lw[2];
    #pragma unroll
    for (int t = 0; t < 2; ++t) lw[t] = lp[t] + __shfl_xor(lp[t], 32);

    const int b = bh >> 4, h = bh & 15;
    #pragma unroll
    for (int t = 0; t < 2; ++t) {
        if (t) __syncthreads();  // WAR: phase-0 reads done before phase-1 writes
        if (w >= 2) {
            const int base = ((w - 2) * 64 + lane) * 33;
            f32x16v* ov = (t == 0) ? &o[0][0] : &o[1][0];
            #pragma unroll
            for (int mt = 0; mt < 2; ++mt)
                #pragma unroll
                for (int r = 0; r < 16; ++r) Lred[base + mt * 16 + r] = ov[mt][r];
            Lred[base + 32] = lw[t];
        }
        __syncthreads();
        if (w < 2) {
            const int base = (w * 64 + lane) * 33;
            f32x16v* ov = (t == 0) ? &o[0][0] : &o[1][0];
            #pragma unroll
            for (int mt = 0; mt < 2; ++mt)
                #pragma unroll
                for (int r = 0; r < 16; ++r) ov[mt][r] += Lred[base + mt * 16 + r];
            float invl = 1.0f / (lw[t] + Lred[base + 32]);
            const int pos = qb * 128 + t * 64 + w * 32 + c;
            float* obase = out + ((size_t)b * NSEQ + pos) * (NH * DH) + h * DH;
            #pragma unroll
            for (int mt = 0; mt < 2; ++mt)
                #pragma unroll
                for (int g = 0; g < 4; ++g) {
                    float4 r4 = make_float4(ov[mt][g * 4 + 0] * invl, ov[mt][g * 4 + 1] * invl,
                                            ov[mt][g * 4 + 2] * invl, ov[mt][g * 4 + 3] * invl);
                    *(float4*)(obase + mt * 32 + g * 8 + hf * 4) = r4;
                }
        }
    }
}

extern "C" void kernel_launch(void* const* d_in, const int* in_sizes, int n_in,
                              void* d_out, int out_size, void* d_ws, size_t ws_size,
                              hipStream_t stream) {
    const float* q  = (const float*)d_in[0];
    const float* k  = (const float*)d_in[1];
    const float* v  = (const float*)d_in[2];
    const float* qs = (const float*)d_in[3];
    const float* ks = (const float*)d_in[4];
    float* outp = (float*)d_out;

    unsigned* qh  = (unsigned*)d_ws;                 // 8 MB
    unsigned* kh  = qh + (size_t)BH * NSEQ * 32;     // 8 MB
    unsigned* vt2 = kh + (size_t)BH * NSEQ * 32;     // 8 MB

    prep_all<<<17408, 256, 0, stream>>>(q, k, v, qs, ks, qh, kh, vt2);
    attn_kernel<<<512, 256, 0, stream>>>(qh, kh, vt2, outp);
}